// Round 1
// baseline (363.797 us; speedup 1.0000x reference)
//
#include <hip/hip_runtime.h>

// GAE backward scan: adv[t] = (r[t] + gamma*v[t+1] - v[t]) + gamma*lambda*adv[t+1]
// rewards, values: [T, B] fp32 row-major; out: [T-1, B] fp32.
// One thread per batch column b; walk t backward. Lane accesses at fixed t are
// contiguous in b -> fully coalesced. Loads for different t are independent of
// the adv recurrence chain, so we batch 8 timesteps of loads (16 outstanding
// global loads/wave) to hide HBM latency at only 2 waves/CU.

#define GAE_T 1024
#define GAE_B 32768

__global__ __launch_bounds__(64) void gae_scan_kernel(
    const float* __restrict__ rewards,
    const float* __restrict__ values,
    float* __restrict__ out) {
    const int b = blockIdx.x * blockDim.x + threadIdx.x;  // 0 .. B-1

    const float gamma = 0.99f;
    const float gl = (float)(0.99 * 0.95);  // match JAX: python-double product, then fp32

    const float* rp = rewards + b;
    const float* vp = values + b;
    float* op = out + b;

    float v_next = vp[(GAE_T - 1) * GAE_B];
    float adv = 0.0f;

    int t = GAE_T - 2;  // 1022; total 1023 outputs (t = 1022 .. 0)

    // Peel 1023 % 8 = 7 iterations.
    for (int k = 0; k < 7; ++k, --t) {
        float v = vp[t * GAE_B];
        float r = rp[t * GAE_B];
        adv = r + gamma * v_next - v + gl * adv;
        op[t * GAE_B] = adv;
        v_next = v;
    }

    // Main loop: 127 batches of 8. Loads batched ahead of the dependent chain.
    for (; t >= 7; t -= 8) {
        float r8[8], v8[8];
#pragma unroll
        for (int k = 0; k < 8; ++k) {
            v8[k] = vp[(t - k) * GAE_B];
            r8[k] = rp[(t - k) * GAE_B];
        }
#pragma unroll
        for (int k = 0; k < 8; ++k) {
            float v = v8[k];
            adv = r8[k] + gamma * v_next - v + gl * adv;
            op[(t - k) * GAE_B] = adv;
            v_next = v;
        }
    }
}

extern "C" void kernel_launch(void* const* d_in, const int* in_sizes, int n_in,
                              void* d_out, int out_size, void* d_ws, size_t ws_size,
                              hipStream_t stream) {
    const float* rewards = (const float*)d_in[0];
    const float* values = (const float*)d_in[1];
    float* out = (float*)d_out;

    // B=32768 columns, 64 threads/block -> 512 blocks = 2 blocks/CU on 256 CUs.
    dim3 grid(GAE_B / 64);
    dim3 block(64);
    gae_scan_kernel<<<grid, block, 0, stream>>>(rewards, values, out);
}